// Round 10
// baseline (42.854 us; speedup 1.0000x reference)
//
#include <hip/hip_runtime.h>

// Embedding scatter v2: out[p,:] = weight[x[p],:], single-pass, 2 barriers.
// Model M2 (verified R6, absmax=0.0): x int32[32768], weight f32[2548][1000]
// (10.2 MB), out f32[32768][1000] (131 MB) -> write-BW-bound.
// R6-R8 gather ~38us; R9 segmented scatter 35.1us (48 barriers/block, x read
// 16x). R10: 510 blocks x 512 thr, 5 vocab rows/block in regs, ONE x scan into
// a flat LDS queue (avg ~64 entries), ONE barrier, 2 store-groups drain with
// NT stores. Kills barrier serialization + scan re-reads.

constexpr int VOCAB   = 2548;
constexpr int ECHUNK  = 250;              // 1000 f32 = 250 x 16 B
constexpr int ROWS    = 64 * 512;         // 32768
constexpr int VPB     = 5;                // vocab rows per block
constexpr int GRID    = 510;              // 510*5 = 2550 >= VOCAB
constexpr int THREADS = 512;              // 2 store-groups of 256
constexpr int QCAP    = 512;              // Poisson(64) mean -> 55 sigma cap

typedef unsigned int u32x4 __attribute__((ext_vector_type(4)));

__global__ __launch_bounds__(THREADS)
void embed_scatter2_kernel(const int* __restrict__ x,
                           const u32x4* __restrict__ w,   // [VOCAB][250]
                           u32x4* __restrict__ out)       // [ROWS][250]
{
    __shared__ int q[QCAP];               // packed (row<<15 | pos)
    __shared__ int qcnt;
    const int v0   = blockIdx.x * VPB;
    const int t    = threadIdx.x;
    const int g    = t >> 8;              // store group 0/1
    const int lane = t & 255;             // chunk id within a row

    if (t == 0) qcnt = 0;

    // Own rows -> registers (each group holds its own copy; L2-local reload).
    u32x4 r0, r1, r2, r3, r4;
    if (lane < ECHUNK) {
        r0 = w[min(v0 + 0, VOCAB - 1) * ECHUNK + lane];
        r1 = w[min(v0 + 1, VOCAB - 1) * ECHUNK + lane];
        r2 = w[min(v0 + 2, VOCAB - 1) * ECHUNK + lane];
        r3 = w[min(v0 + 3, VOCAB - 1) * ECHUNK + lane];
        r4 = w[min(v0 + 4, VOCAB - 1) * ECHUNK + lane];
    }
    __syncthreads();                      // qcnt=0 visible before scan atomics

    // Single scan of x (128 KB, L2-resident, coalesced int4).
    const int4* x4 = (const int4*)x;
    #pragma unroll
    for (int u = 0; u < (ROWS / 4) / THREADS; ++u) {      // 16 iters
        const int  i4   = u * THREADS + t;
        const int4 xv   = x4[i4];
        const int  base = i4 * 4;
        const int  e[4] = { xv.x, xv.y, xv.z, xv.w };
        #pragma unroll
        for (int j = 0; j < 4; ++j) {
            const unsigned d = (unsigned)(e[j] - v0);
            if (d < (unsigned)VPB) {                      // ~64 hits/block
                const int slot = atomicAdd(&qcnt, 1);
                if (slot < QCAP) q[slot] = (int)((d << 15) | (base + j));
            }
        }
    }
    __syncthreads();                      // the only post-scan barrier

    // Drain queue: groups take entries round-robin; wave-uniform row switch
    // (no runtime-indexed register array -> no scratch).
    const int nq = min(qcnt, QCAP);
    if (lane < ECHUNK) {
        for (int e = g; e < nq; e += 2) {
            const int ent = q[e];                         // LDS broadcast
            u32x4* dst = &out[(ent & 32767) * ECHUNK + lane];
            switch (ent >> 15) {
                case 0:  __builtin_nontemporal_store(r0, dst); break;
                case 1:  __builtin_nontemporal_store(r1, dst); break;
                case 2:  __builtin_nontemporal_store(r2, dst); break;
                case 3:  __builtin_nontemporal_store(r3, dst); break;
                default: __builtin_nontemporal_store(r4, dst); break;
            }
        }
    }
}

extern "C" void kernel_launch(void* const* d_in, const int* in_sizes, int n_in,
                              void* d_out, int out_size, void* d_ws, size_t ws_size,
                              hipStream_t stream) {
    // x = smallest input (32768 elems), weight = largest (2,548,000 elems).
    int xi = 0, wi = 0;
    for (int i = 1; i < n_in; ++i) {
        if (in_sizes[i] < in_sizes[xi]) xi = i;
        if (in_sizes[i] > in_sizes[wi]) wi = i;
    }
    if (xi == wi && n_in >= 2) { xi = 0; wi = 1; }

    const int*   x = (const int*)d_in[xi];
    const u32x4* w = (const u32x4*)d_in[wi];
    u32x4*       o = (u32x4*)d_out;

    embed_scatter2_kernel<<<GRID, THREADS, 0, stream>>>(x, w, o);
}

// Round 11
// 36.072 us; speedup vs baseline: 1.1880x; 1.1880x over previous
//
#include <hip/hip_runtime.h>

// Embedding scatter v3: R9's proven geometry + software pipeline.
// Model M2 (verified R6, absmax=0.0): x int32[32768], weight f32[2548][1000]
// (10.2 MB), out f32[32768][1000] (131 MB) -> write-BW-bound (floor ~20.5us).
// R9 (48 barriers/block): 35.1us. R10 (fat blocks, serialized drain): 42.9us.
// R11: 1274 blocks x 256 thr x VPB=2; ping-pong per-segment queues; counters
// pre-reset once (16 per-segment slots -> no reset barrier/race); each phase:
// issue scan loads -> flush prev segment (stores overlap loads) -> push ->
// barrier. 17 barriers total, scan/flush overlapped.

constexpr int VOCAB   = 2548;
constexpr int ECHUNK  = 250;               // 1000 f32 = 250 x 16 B
constexpr int ROWS    = 64 * 512;          // 32768
constexpr int VPB     = 2;                 // vocab rows per block
constexpr int GRID    = VOCAB / VPB;       // 1274, exact
constexpr int THREADS = 256;
constexpr int SEG     = 2048;              // positions per segment
constexpr int NSEG    = ROWS / SEG;        // 16, exact
constexpr int QCAP    = 64;                // ~50 sigma for Poisson(0.8)/row/seg

typedef unsigned int u32x4 __attribute__((ext_vector_type(4)));

__global__ __launch_bounds__(THREADS)
void embed_scatter3_kernel(const int* __restrict__ x,
                           const u32x4* __restrict__ w,   // [VOCAB][250]
                           u32x4* __restrict__ out)       // [ROWS][250]
{
    __shared__ int q[2][VPB][QCAP];        // ping-pong position queues
    __shared__ int cnt[NSEG][VPB];         // one counter slot per segment
    const int v0 = blockIdx.x * VPB;
    const int t  = threadIdx.x;

    if (t < NSEG * VPB) ((int*)cnt)[t] = 0;   // reset ALL counters once

    // Own rows -> registers (read once; lane = chunk id).
    u32x4 r0, r1;
    if (t < ECHUNK) {
        r0 = w[(v0 + 0) * ECHUNK + t];
        r1 = w[(v0 + 1) * ECHUNK + t];
    }
    __syncthreads();                       // counters + nothing else pending

    const int4* x4 = (const int4*)x;

    for (int s = 0; s < NSEG; ++s) {
        // (a) issue this segment's scan loads (L2, long latency).
        int4 xv[2]; int base[2];
        #pragma unroll
        for (int u = 0; u < 2; ++u) {      // SEG/4/THREADS = 2
            const int i4 = s * (SEG / 4) + u * THREADS + t;
            xv[u]   = x4[i4];
            base[u] = i4 * 4;
        }

        // (b) flush previous segment while loads are in flight.
        if (s > 0) {
            const int pb = (s - 1) & 1;
            const int n0 = min(cnt[s - 1][0], QCAP);
            const int n1 = min(cnt[s - 1][1], QCAP);
            if (t < ECHUNK) {
                for (int j = 0; j < n0; ++j)
                    __builtin_nontemporal_store(r0, &out[q[pb][0][j] * ECHUNK + t]);
                for (int j = 0; j < n1; ++j)
                    __builtin_nontemporal_store(r1, &out[q[pb][1][j] * ECHUNK + t]);
            }
        }

        // (c) push scan hits into this segment's queue.
        const int cb = s & 1;
        #pragma unroll
        for (int u = 0; u < 2; ++u) {
            const int e[4] = { xv[u].x, xv[u].y, xv[u].z, xv[u].w };
            #pragma unroll
            for (int j = 0; j < 4; ++j) {
                const unsigned d = (unsigned)(e[j] - v0);
                if (d < (unsigned)VPB) {
                    const int slot = atomicAdd(&cnt[s][d], 1);
                    if (slot < QCAP) {
                        q[cb][d][slot] = base[u] + j;
                    } else {               // ~0-probability safety net
                        const int p = base[u] + j;
                        for (int c = 0; c < ECHUNK; ++c)
                            out[p * ECHUNK + c] = w[(v0 + (int)d) * ECHUNK + c];
                    }
                }
            }
        }
        __syncthreads();                   // one barrier per segment
    }

    // Final flush: segment NSEG-1.
    {
        const int pb = (NSEG - 1) & 1;
        const int n0 = min(cnt[NSEG - 1][0], QCAP);
        const int n1 = min(cnt[NSEG - 1][1], QCAP);
        if (t < ECHUNK) {
            for (int j = 0; j < n0; ++j)
                __builtin_nontemporal_store(r0, &out[q[pb][0][j] * ECHUNK + t]);
            for (int j = 0; j < n1; ++j)
                __builtin_nontemporal_store(r1, &out[q[pb][1][j] * ECHUNK + t]);
        }
    }
}

extern "C" void kernel_launch(void* const* d_in, const int* in_sizes, int n_in,
                              void* d_out, int out_size, void* d_ws, size_t ws_size,
                              hipStream_t stream) {
    // x = smallest input (32768 elems), weight = largest (2,548,000 elems).
    int xi = 0, wi = 0;
    for (int i = 1; i < n_in; ++i) {
        if (in_sizes[i] < in_sizes[xi]) xi = i;
        if (in_sizes[i] > in_sizes[wi]) wi = i;
    }
    if (xi == wi && n_in >= 2) { xi = 0; wi = 1; }

    const int*   x = (const int*)d_in[xi];
    const u32x4* w = (const u32x4*)d_in[wi];
    u32x4*       o = (u32x4*)d_out;

    embed_scatter3_kernel<<<GRID, THREADS, 0, stream>>>(x, w, o);
}

// Round 12
// 35.275 us; speedup vs baseline: 1.2149x; 1.0226x over previous
//
#include <hip/hip_runtime.h>

// FINAL (best-known, R9 = 35.1us): embedding scatter, out[p,:] = weight[x[p],:].
// Model M2 (verified R6, absmax=0.0): x int32[32768], weight f32[2548][1000]
// (10.2 MB), out f32[32768][1000] (131 MB) -> write-BW-bound.
//
// Roofline accounting (R6-R11, six independent designs at 35-43us):
//   131 MB HBM write @ ~6.9 TB/s (fill-kernel demonstrated rate) ~= 19-20us
//   + ~2us reads/tail + ~10us graph-replay/launch overhead => ~32-35us floor.
// Gather variants (read 131 MB through EA): 37.9-39.7us. This scatter reads
// weight ONCE (10.2 MB) via per-vocab-row ownership: 1274 blocks x 2 rows,
// rows held in registers, x scanned in 16 segments with LDS position queues,
// block-wide coalesced NT row-stores. Barrier-reduction and pipelining
// variants (R10/R11) did NOT improve on this -> practical roofline.

constexpr int VOCAB   = 2548;
constexpr int ECHUNK  = 250;              // 1000 f32 = 250 x 16 B
constexpr int ROWS    = 64 * 512;         // 32768
constexpr int VPB     = 2;                // vocab rows per block
constexpr int GRID    = VOCAB / VPB;      // 1274, exact
constexpr int THREADS = 256;
constexpr int SEG     = 2048;             // x entries per scan segment
constexpr int NSEG    = ROWS / SEG;       // 16, exact

typedef unsigned int u32x4 __attribute__((ext_vector_type(4)));

__global__ __launch_bounds__(THREADS)
void embed_scatter_kernel(const int* __restrict__ x,
                          const u32x4* __restrict__ w,   // [VOCAB][250]
                          u32x4* __restrict__ out)       // [ROWS][250]
{
    __shared__ int q[VPB][SEG];           // position queues (cap=SEG: overflow
    __shared__ int qcnt[VPB];             //  is structurally impossible)
    const int v0 = blockIdx.x * VPB;
    const int t  = threadIdx.x;

    // Own rows -> registers, read exactly once per block (thread t = chunk t).
    u32x4 row[VPB];
    if (t < ECHUNK) {
        #pragma unroll
        for (int k = 0; k < VPB; ++k) row[k] = w[(v0 + k) * ECHUNK + t];
    }

    const int4* x4 = (const int4*)x;      // 16B-aligned index loads

    for (int s = 0; s < NSEG; ++s) {
        if (t < VPB) qcnt[t] = 0;
        __syncthreads();

        // Scan this segment of x (L2-resident, coalesced int4 loads).
        #pragma unroll
        for (int u = 0; u < SEG / 4 / THREADS; ++u) {    // = 2
            const int i4   = s * (SEG / 4) + u * THREADS + t;
            const int4 xv  = x4[i4];
            const int base = i4 * 4;
            const int e[4] = { xv.x, xv.y, xv.z, xv.w };
            #pragma unroll
            for (int j = 0; j < 4; ++j) {
                const unsigned d = (unsigned)(e[j] - v0);
                if (d < (unsigned)VPB) {
                    const int slot = atomicAdd(&qcnt[d], 1);  // rare (~1.6/seg)
                    q[d][slot] = base + j;
                }
            }
        }
        __syncthreads();

        // Flush: block-wide coalesced NT stores of the register-held row.
        #pragma unroll
        for (int k = 0; k < VPB; ++k) {
            const int n = qcnt[k];
            for (int j = 0; j < n; ++j) {            // uniform branch (LDS cnt)
                const int p = q[k][j];
                if (t < ECHUNK)
                    __builtin_nontemporal_store(row[k], &out[p * ECHUNK + t]);
            }
        }
        __syncthreads();                  // protect qcnt/q before next reset
    }
}

extern "C" void kernel_launch(void* const* d_in, const int* in_sizes, int n_in,
                              void* d_out, int out_size, void* d_ws, size_t ws_size,
                              hipStream_t stream) {
    // x = smallest input (32768 elems), weight = largest (2,548,000 elems).
    int xi = 0, wi = 0;
    for (int i = 1; i < n_in; ++i) {
        if (in_sizes[i] < in_sizes[xi]) xi = i;
        if (in_sizes[i] > in_sizes[wi]) wi = i;
    }
    if (xi == wi && n_in >= 2) { xi = 0; wi = 1; }

    const int*   x = (const int*)d_in[xi];
    const u32x4* w = (const u32x4*)d_in[wi];
    u32x4*       o = (u32x4*)d_out;

    embed_scatter_kernel<<<GRID, THREADS, 0, stream>>>(x, w, o);
}